// Round 1
// baseline (5600.229 us; speedup 1.0000x reference)
//
#include <hip/hip_runtime.h>
#include <hip/hip_bf16.h>

// GCN forward: 3 layers on MI355X.
// N=100000 nodes, E=3200000 edges, IN_C=128, HID=16, OUT=1.

constexpr int N_NODES = 100000;
constexpr int N_EDGES = 3200000;
constexpr int INC = 128;
constexpr int HID = 16;

// ---------------- degree / norm ----------------

__global__ void k_init_deg(float* __restrict__ deg) {
    int i = blockIdx.x * blockDim.x + threadIdx.x;
    if (i < N_NODES) deg[i] = 1.0f;  // self-loop weight
}

__global__ void k_accum_deg(const int* __restrict__ col,
                            const float* __restrict__ ew,
                            float* __restrict__ deg) {
    int e = blockIdx.x * blockDim.x + threadIdx.x;
    if (e < N_EDGES) atomicAdd(&deg[col[e]], ew[e]);
}

__global__ void k_dinv(float* __restrict__ deg) {
    int i = blockIdx.x * blockDim.x + threadIdx.x;
    if (i < N_NODES) deg[i] = rsqrtf(deg[i]);  // deg >= 1 always (self loop)
}

__global__ void k_norm(const int* __restrict__ row, const int* __restrict__ col,
                       const float* __restrict__ ew, const float* __restrict__ dinv,
                       float* __restrict__ norm) {
    int e = blockIdx.x * blockDim.x + threadIdx.x;
    if (e < N_EDGES) norm[e] = dinv[row[e]] * ew[e] * dinv[col[e]];
}

// ---------------- GEMM x@W1 : [N,128]@[128,16] ----------------
// Block = 256 threads handles 16 nodes; W1 (8KB) + x-tile (8KB) in LDS.

__global__ __launch_bounds__(256) void k_gemm_in(const float* __restrict__ x,
                                                 const float* __restrict__ W1,
                                                 float* __restrict__ t) {
    __shared__ float ws[INC * HID];   // 128*16 = 2048 floats
    __shared__ float xs[16 * INC];    // 16 nodes * 128
    int tid = threadIdx.x;
    int nb = blockIdx.x * 16;
    for (int i = tid; i < INC * HID; i += 256) ws[i] = W1[i];
    const float* xblk = x + (size_t)nb * INC;
    for (int i = tid; i < 16 * INC; i += 256) xs[i] = xblk[i];
    __syncthreads();
    int ln = tid >> 4;        // local node 0..15
    int c  = tid & 15;        // out channel 0..15
    float acc = 0.f;
#pragma unroll 16
    for (int k = 0; k < INC; ++k) acc += xs[ln * INC + k] * ws[k * HID + c];
    t[(size_t)(nb + ln) * HID + c] = acc;
}

// ---------------- self-loop init of agg ----------------
// agg[i][c] = dinv[i]^2 * t[i][c]

__global__ void k_selfinit(const float* __restrict__ t,
                           const float* __restrict__ dinv,
                           float* __restrict__ agg) {
    int idx = blockIdx.x * blockDim.x + threadIdx.x;
    if (idx < N_NODES * HID) {
        int i = idx >> 4;
        float d = dinv[i];
        agg[idx] = d * d * t[idx];
    }
}

// ---------------- edge scatter: agg[col] += norm * t[row] ----------------

__global__ void k_scatter(const int* __restrict__ row, const int* __restrict__ col,
                          const float* __restrict__ norm, const float* __restrict__ t,
                          float* __restrict__ agg) {
    int e = blockIdx.x * blockDim.x + threadIdx.x;
    if (e >= N_EDGES) return;
    int r = row[e], cd = col[e];
    float nm = norm[e];
    const float4* src = (const float4*)(t + (size_t)r * HID);
    float* dst = agg + (size_t)cd * HID;
#pragma unroll
    for (int q = 0; q < 4; ++q) {
        float4 v = src[q];
        atomicAdd(dst + q * 4 + 0, nm * v.x);
        atomicAdd(dst + q * 4 + 1, nm * v.y);
        atomicAdd(dst + q * 4 + 2, nm * v.z);
        atomicAdd(dst + q * 4 + 3, nm * v.w);
    }
}

// ---------------- bias + relu ----------------

__global__ void k_bias_relu(const float* __restrict__ agg,
                            const float* __restrict__ b,
                            float* __restrict__ h) {
    int idx = blockIdx.x * blockDim.x + threadIdx.x;
    if (idx < N_NODES * HID) {
        h[idx] = fmaxf(agg[idx] + b[idx & 15], 0.0f);
    }
}

// ---------------- GEMM h@W : [N,16]@[16,16] ----------------

__global__ __launch_bounds__(256) void k_gemm_hid(const float* __restrict__ h,
                                                  const float* __restrict__ W,
                                                  float* __restrict__ t) {
    __shared__ float ws[HID * HID];
    int tid = threadIdx.x;
    if (tid < HID * HID) ws[tid] = W[tid];
    __syncthreads();
    int idx = blockIdx.x * 256 + tid;
    if (idx >= N_NODES * HID) return;
    int i = idx >> 4, c = idx & 15;
    const float* hr = h + (size_t)i * HID;
    float acc = 0.f;
#pragma unroll
    for (int k = 0; k < HID; ++k) acc += hr[k] * ws[k * HID + c];
    t[idx] = acc;
}

// ---------------- output: out[i] = h[i,:]·Wout + bout ----------------

__global__ void k_out(const float* __restrict__ h, const float* __restrict__ Wout,
                      const float* __restrict__ bout, float* __restrict__ out) {
    int i = blockIdx.x * blockDim.x + threadIdx.x;
    if (i >= N_NODES) return;
    float acc = bout[0];
#pragma unroll
    for (int c = 0; c < HID; ++c) acc += h[(size_t)i * HID + c] * Wout[c];
    out[i] = acc;
}

extern "C" void kernel_launch(void* const* d_in, const int* in_sizes, int n_in,
                              void* d_out, int out_size, void* d_ws, size_t ws_size,
                              hipStream_t stream) {
    const float* x    = (const float*)d_in[0];
    const int*   eidx = (const int*)d_in[1];
    const float* ew   = (const float*)d_in[2];
    // d_in[3]=y, d_in[4]=batch (unused)
    const float* W1   = (const float*)d_in[5];
    const float* b1   = (const float*)d_in[6];
    const float* W2   = (const float*)d_in[7];
    const float* b2   = (const float*)d_in[8];
    const float* Wout = (const float*)d_in[9];
    const float* bout = (const float*)d_in[10];
    float* out = (float*)d_out;

    const int* row = eidx;             // edge_index[0]
    const int* col = eidx + N_EDGES;   // edge_index[1]

    // workspace layout (floats)
    float* ws = (float*)d_ws;
    float* deg  = ws;                          // N            (becomes dinv)
    float* norm = deg + N_NODES;               // E
    float* t    = norm + N_EDGES;              // N*16  (x@W product)
    float* h    = t + (size_t)N_NODES * HID;   // N*16  (post-activation)
    float* agg  = h + (size_t)N_NODES * HID;   // N*16

    const int B = 256;
    const int gN   = (N_NODES + B - 1) / B;          // 391
    const int gE   = (N_EDGES + B - 1) / B;          // 12500
    const int gNH  = (N_NODES * HID + B - 1) / B;    // 6250
    const int gGin = N_NODES / 16;                   // 6250

    // degree + norm
    k_init_deg<<<gN, B, 0, stream>>>(deg);
    k_accum_deg<<<gE, B, 0, stream>>>(col, ew, deg);
    k_dinv<<<gN, B, 0, stream>>>(deg);
    k_norm<<<gE, B, 0, stream>>>(row, col, ew, deg, norm);

    // layer 1
    k_gemm_in<<<gGin, B, 0, stream>>>(x, W1, t);
    k_selfinit<<<gNH, B, 0, stream>>>(t, deg, agg);
    k_scatter<<<gE, B, 0, stream>>>(row, col, norm, t, agg);
    k_bias_relu<<<gNH, B, 0, stream>>>(agg, b1, h);

    // layer 2
    k_gemm_hid<<<gNH, B, 0, stream>>>(h, W2, t);
    k_selfinit<<<gNH, B, 0, stream>>>(t, deg, agg);
    k_scatter<<<gE, B, 0, stream>>>(row, col, norm, t, agg);
    k_bias_relu<<<gNH, B, 0, stream>>>(agg, b2, h);

    // output projection
    k_out<<<gN, B, 0, stream>>>(h, Wout, bout, out);
}

// Round 3
// 668.054 us; speedup vs baseline: 8.3829x; 8.3829x over previous
//
#include <hip/hip_runtime.h>
#include <hip/hip_bf16.h>

// GCN forward, CSR-gather formulation (no float atomics).
// N=100000 nodes, E=3200000 edges, IN_C=128, HID=16, OUT=1.

constexpr int N_NODES = 100000;
constexpr int N_EDGES = 3200000;
constexpr int INC = 128;
constexpr int HID = 16;

constexpr int NREP   = 8;                    // replicated buckets per node
constexpr int NKEY   = N_NODES * NREP;       // 800000
constexpr int SCAN_N = NKEY + 1;             // 800001 (last entry = E after scan)
constexpr int SCAN_B = 1024;
constexpr int SCAN_NB = (SCAN_N + SCAN_B - 1) / SCAN_B;   // 782

// ---------------- utility ----------------

__global__ void k_zero(int* __restrict__ p, int n) {
    int i = blockIdx.x * blockDim.x + threadIdx.x;
    if (i < n) p[i] = 0;
}

// ---------------- pass 1: histogram with rank capture ----------------
// key = col*8 + rep  (rep = per-block replica) -> 8x less cacheline contention.

__global__ void k_hist(const int* __restrict__ col,
                       int* __restrict__ cnt, int* __restrict__ rank) {
    int e = blockIdx.x * 256 + threadIdx.x;
    if (e >= N_EDGES) return;
    int key = (col[e] << 3) | ((e >> 8) & 7);
    rank[e] = atomicAdd(&cnt[key], 1);
}

// ---------------- two-level exclusive scan over cnt[SCAN_N] ----------------

__global__ __launch_bounds__(1024) void k_scan1(int* __restrict__ cnt,
                                                int* __restrict__ bsum) {
    __shared__ int s[SCAN_B];
    int gid = blockIdx.x * SCAN_B + threadIdx.x;
    int v = (gid < SCAN_N) ? cnt[gid] : 0;
    s[threadIdx.x] = v;
    __syncthreads();
    for (int off = 1; off < SCAN_B; off <<= 1) {
        int t = (threadIdx.x >= off) ? s[threadIdx.x - off] : 0;
        __syncthreads();
        s[threadIdx.x] += t;
        __syncthreads();
    }
    if (gid < SCAN_N) cnt[gid] = s[threadIdx.x] - v;    // exclusive within block
    if (threadIdx.x == SCAN_B - 1) bsum[blockIdx.x] = s[SCAN_B - 1];
}

__global__ void k_scan2(int* __restrict__ bsum) {
    if (blockIdx.x == 0 && threadIdx.x == 0) {
        int acc = 0;
        for (int i = 0; i < SCAN_NB; ++i) { int v = bsum[i]; bsum[i] = acc; acc += v; }
    }
}

__global__ __launch_bounds__(1024) void k_scan3(int* __restrict__ cnt,
                                                const int* __restrict__ bsum) {
    int gid = blockIdx.x * SCAN_B + threadIdx.x;
    if (gid < SCAN_N) cnt[gid] += bsum[blockIdx.x];
}

// ---------------- pass 2: placement (scatter edge data into CSR) ----------------

__global__ void k_place(const int* __restrict__ row, const int* __restrict__ col,
                        const float* __restrict__ ew,
                        const int* __restrict__ start, const int* __restrict__ rank,
                        int* __restrict__ srow, float* __restrict__ sew) {
    int e = blockIdx.x * 256 + threadIdx.x;
    if (e >= N_EDGES) return;
    int key = (col[e] << 3) | ((e >> 8) & 7);
    int p = start[key] + rank[e];
    srow[p] = row[e];
    sew[p] = ew[e];
}

// ---------------- degree -> dinv (gather, 16 lanes per node) ----------------

__global__ __launch_bounds__(256) void k_deg(const int* __restrict__ start,
                                             const float* __restrict__ sew,
                                             float* __restrict__ dinv) {
    int tid = threadIdx.x;
    int i = blockIdx.x * 16 + (tid >> 4);
    if (i >= N_NODES) return;
    int l = tid & 15;
    int s = start[i << 3], e2 = start[(i + 1) << 3];
    float acc = 0.f;
    for (int p = s + l; p < e2; p += 16) acc += sew[p];
#pragma unroll
    for (int m = 1; m < 16; m <<= 1) acc += __shfl_xor(acc, m);
    if (l == 0) dinv[i] = rsqrtf(1.0f + acc);   // +1 = self-loop weight
}

// ---------------- precompute sw[p] = dinv[srow[p]] * ew[p] (in-place) --------

__global__ void k_sw(const int* __restrict__ srow, float* __restrict__ sew,
                     const float* __restrict__ dinv) {
    int p = blockIdx.x * 256 + threadIdx.x;
    if (p < N_EDGES) sew[p] = dinv[srow[p]] * sew[p];
}

// ---------------- GEMM x@W1 : [N,128]@[128,16] ----------------

__global__ __launch_bounds__(256) void k_gemm_in(const float* __restrict__ x,
                                                 const float* __restrict__ W1,
                                                 float* __restrict__ t) {
    __shared__ float ws[INC * HID];
    __shared__ float xs[16 * INC];
    int tid = threadIdx.x;
    int nb = blockIdx.x * 16;
    for (int i = tid; i < INC * HID; i += 256) ws[i] = W1[i];
    const float* xblk = x + (size_t)nb * INC;
    for (int i = tid; i < 16 * INC; i += 256) xs[i] = xblk[i];
    __syncthreads();
    int ln = tid >> 4, c = tid & 15;
    float acc = 0.f;
#pragma unroll 16
    for (int k = 0; k < INC; ++k) acc += xs[ln * INC + k] * ws[k * HID + c];
    t[(size_t)(nb + ln) * HID + c] = acc;
}

// ---------------- aggregation (gather) + bias + relu ----------------
// h[i][c] = relu( dinv[i]*( sum_p sw[p]*t[srow[p]][c] + dinv[i]*t[i][c] ) + b[c] )

__global__ __launch_bounds__(256) void k_agg(const int* __restrict__ start,
                                             const int* __restrict__ srow,
                                             const float* __restrict__ sw,
                                             const float* __restrict__ dinv,
                                             const float* __restrict__ t,
                                             const float* __restrict__ b,
                                             float* __restrict__ h) {
    int tid = threadIdx.x;
    int i = blockIdx.x * 16 + (tid >> 4);
    if (i >= N_NODES) return;
    int c = tid & 15;
    int s = start[i << 3], e2 = start[(i + 1) << 3];
    float acc = 0.f;
    for (int p = s; p < e2; ++p) {
        acc += sw[p] * t[((size_t)srow[p] << 4) + c];
    }
    float d = dinv[i];
    float self = d * t[((size_t)i << 4) + c];
    float v = d * (acc + self) + b[c];
    h[((size_t)i << 4) + c] = fmaxf(v, 0.f);
}

// ---------------- GEMM h@W : [N,16]@[16,16] ----------------

__global__ __launch_bounds__(256) void k_gemm_hid(const float* __restrict__ h,
                                                  const float* __restrict__ W,
                                                  float* __restrict__ t) {
    __shared__ float ws[HID * HID];
    int tid = threadIdx.x;
    if (tid < HID * HID) ws[tid] = W[tid];
    __syncthreads();
    int idx = blockIdx.x * 256 + tid;
    if (idx >= N_NODES * HID) return;
    int i = idx >> 4, c = idx & 15;
    const float* hr = h + (size_t)i * HID;
    float acc = 0.f;
#pragma unroll
    for (int k = 0; k < HID; ++k) acc += hr[k] * ws[k * HID + c];
    t[idx] = acc;
}

// ---------------- output: out[i] = h[i,:]·Wout + bout ----------------

__global__ void k_out(const float* __restrict__ h, const float* __restrict__ Wout,
                      const float* __restrict__ bout, float* __restrict__ out) {
    int i = blockIdx.x * blockDim.x + threadIdx.x;
    if (i >= N_NODES) return;
    float acc = bout[0];
#pragma unroll
    for (int c = 0; c < HID; ++c) acc += h[(size_t)i * HID + c] * Wout[c];
    out[i] = acc;
}

extern "C" void kernel_launch(void* const* d_in, const int* in_sizes, int n_in,
                              void* d_out, int out_size, void* d_ws, size_t ws_size,
                              hipStream_t stream) {
    const float* x    = (const float*)d_in[0];
    const int*   eidx = (const int*)d_in[1];
    const float* ew   = (const float*)d_in[2];
    const float* W1   = (const float*)d_in[5];
    const float* b1   = (const float*)d_in[6];
    const float* W2   = (const float*)d_in[7];
    const float* b2   = (const float*)d_in[8];
    const float* Wout = (const float*)d_in[9];
    const float* bout = (const float*)d_in[10];
    float* out = (float*)d_out;

    const int* row = eidx;             // edge_index[0] (src)
    const int* col = eidx + N_EDGES;   // edge_index[1] (dst)

    // workspace layout (4B units)
    int*   cnt  = (int*)d_ws;                         // SCAN_N (rounded to 800008)
    int*   bsum = cnt + 800008;                       // 1024
    float* dinv = (float*)(bsum + 1024);              // N
    int*   srow = (int*)(dinv + N_NODES);             // E
    float* sew  = (float*)(srow + N_EDGES);           // E
    int*   rank = (int*)(sew + N_EDGES);              // E  (dead after k_place)
    float* t    = (float*)rank;                       // N*16  (aliases rank)
    float* h    = t + (size_t)N_NODES * HID;          // N*16  (aliases rank)

    const int B = 256;
    const int gE  = (N_EDGES + B - 1) / B;            // 12500
    const int gN16 = N_NODES / 16;                    // 6250 (N divisible by 16)
    const int gNH = (N_NODES * HID + B - 1) / B;      // 6250
    const int gN  = (N_NODES + B - 1) / B;            // 391
    const int gZ  = (SCAN_N + B - 1) / B;

    // CSR build
    k_zero<<<gZ, B, 0, stream>>>(cnt, SCAN_N);
    k_hist<<<gE, B, 0, stream>>>(col, cnt, rank);
    k_scan1<<<SCAN_NB, SCAN_B, 0, stream>>>(cnt, bsum);
    k_scan2<<<1, 64, 0, stream>>>(bsum);
    k_scan3<<<SCAN_NB, SCAN_B, 0, stream>>>(cnt, bsum);
    k_place<<<gE, B, 0, stream>>>(row, col, ew, cnt, rank, srow, sew);

    // normalization
    k_deg<<<gN16, B, 0, stream>>>(cnt, sew, dinv);
    k_sw<<<gE, B, 0, stream>>>(srow, sew, dinv);

    // layer 1
    k_gemm_in<<<gN16, B, 0, stream>>>(x, W1, t);
    k_agg<<<gN16, B, 0, stream>>>(cnt, srow, sew, dinv, t, b1, h);

    // layer 2
    k_gemm_hid<<<gNH, B, 0, stream>>>(h, W2, t);
    k_agg<<<gN16, B, 0, stream>>>(cnt, srow, sew, dinv, t, b2, h);

    // output projection
    k_out<<<gN, B, 0, stream>>>(h, Wout, bout, out);
}

// Round 4
// 583.470 us; speedup vs baseline: 9.5981x; 1.1450x over previous
//
#include <hip/hip_runtime.h>
#include <hip/hip_bf16.h>

// GCN forward, CSR-gather formulation, packed int2 edge payload.
// N=100000 nodes, E=3200000 edges, IN_C=128, HID=16, OUT=1.

constexpr int N_NODES = 100000;
constexpr int N_EDGES = 3200000;
constexpr int INC = 128;
constexpr int HID = 16;

constexpr int NREP   = 8;                    // replicated buckets per node
constexpr int NKEY   = N_NODES * NREP;       // 800000
constexpr int SCAN_N = NKEY + 1;             // 800001 (last = E after scan)
constexpr int SCAN_B = 1024;
constexpr int SCAN_NB = (SCAN_N + SCAN_B - 1) / SCAN_B;   // 782

// ---------------- utility ----------------

__global__ void k_zero(int* __restrict__ p, int n) {
    int i = blockIdx.x * blockDim.x + threadIdx.x;
    if (i < n) p[i] = 0;
}

// ---------------- pass 1: histogram with rank capture ----------------

__global__ void k_hist(const int* __restrict__ col,
                       int* __restrict__ cnt, int* __restrict__ rank) {
    int e = blockIdx.x * 256 + threadIdx.x;
    if (e >= N_EDGES) return;
    int key = (col[e] << 3) | ((e >> 8) & 7);
    rank[e] = atomicAdd(&cnt[key], 1);
}

// ---------------- two-level exclusive scan over cnt[SCAN_N] ----------------

__global__ __launch_bounds__(1024) void k_scan1(int* __restrict__ cnt,
                                                int* __restrict__ bsum) {
    __shared__ int s[SCAN_B];
    int gid = blockIdx.x * SCAN_B + threadIdx.x;
    int v = (gid < SCAN_N) ? cnt[gid] : 0;
    s[threadIdx.x] = v;
    __syncthreads();
    for (int off = 1; off < SCAN_B; off <<= 1) {
        int t = (threadIdx.x >= off) ? s[threadIdx.x - off] : 0;
        __syncthreads();
        s[threadIdx.x] += t;
        __syncthreads();
    }
    if (gid < SCAN_N) cnt[gid] = s[threadIdx.x] - v;
    if (threadIdx.x == SCAN_B - 1) bsum[blockIdx.x] = s[SCAN_B - 1];
}

__global__ void k_scan2(int* __restrict__ bsum) {
    if (blockIdx.x == 0 && threadIdx.x == 0) {
        int acc = 0;
        for (int i = 0; i < SCAN_NB; ++i) { int v = bsum[i]; bsum[i] = acc; acc += v; }
    }
}

__global__ __launch_bounds__(1024) void k_scan3(int* __restrict__ cnt,
                                                const int* __restrict__ bsum) {
    int gid = blockIdx.x * SCAN_B + threadIdx.x;
    if (gid < SCAN_N) cnt[gid] += bsum[blockIdx.x];
}

// ---------------- pass 2: placement — single 8B scattered store ----------------

__global__ void k_place(const int* __restrict__ row, const int* __restrict__ col,
                        const float* __restrict__ ew,
                        const int* __restrict__ start, const int* __restrict__ rank,
                        int2* __restrict__ pay) {
    int e = blockIdx.x * 256 + threadIdx.x;
    if (e >= N_EDGES) return;
    int key = (col[e] << 3) | ((e >> 8) & 7);
    int p = start[key] + rank[e];
    pay[p] = make_int2(row[e], __float_as_int(ew[e]));
}

// ---------------- degree -> dinv (one wave per node) ----------------

__global__ __launch_bounds__(256) void k_deg(const int* __restrict__ start,
                                             const int2* __restrict__ pay,
                                             float* __restrict__ dinv) {
    int i = (blockIdx.x * 256 + threadIdx.x) >> 6;
    if (i >= N_NODES) return;
    int l = threadIdx.x & 63;
    int s = start[i << 3], e2 = start[(i + 1) << 3];
    float acc = 0.f;
    for (int p = s + l; p < e2; p += 64) acc += __int_as_float(pay[p].y);
#pragma unroll
    for (int m = 32; m >= 1; m >>= 1) acc += __shfl_xor(acc, m);
    if (l == 0) dinv[i] = rsqrtf(1.0f + acc);   // +1 = self-loop weight
}

// ---------------- GEMM x@W1, epilogue x dinv: t'[i][c] = dinv[i]*(x@W1)[i][c] --

__global__ __launch_bounds__(256) void k_gemm_in(const float* __restrict__ x,
                                                 const float* __restrict__ W1,
                                                 const float* __restrict__ dinv,
                                                 float* __restrict__ t) {
    __shared__ float ws[INC * HID];
    __shared__ float xs[16 * INC];
    int tid = threadIdx.x;
    int nb = blockIdx.x * 16;
    for (int i = tid; i < INC * HID; i += 256) ws[i] = W1[i];
    const float* xblk = x + (size_t)nb * INC;
    for (int i = tid; i < 16 * INC; i += 256) xs[i] = xblk[i];
    __syncthreads();
    int ln = tid >> 4, c = tid & 15;
    float acc = 0.f;
#pragma unroll 16
    for (int k = 0; k < INC; ++k) acc += xs[ln * INC + k] * ws[k * HID + c];
    t[(size_t)(nb + ln) * HID + c] = dinv[nb + ln] * acc;
}

// ---------------- aggregation, one wave per node ----------------
// lanes = 4 edge-slots x 16 channels.  h = relu(dinv[i]*(acc + t'[i][c]) + b[c])

__global__ __launch_bounds__(256) void k_agg_mid(const int* __restrict__ start,
                                                 const int2* __restrict__ pay,
                                                 const float* __restrict__ dinv,
                                                 const float* __restrict__ t,
                                                 const float* __restrict__ b,
                                                 float* __restrict__ h) {
    int i = (blockIdx.x * 256 + threadIdx.x) >> 6;
    if (i >= N_NODES) return;
    int lane = threadIdx.x & 63;
    int eo = lane >> 4;       // 0..3
    int c  = lane & 15;
    int s = start[i << 3], e2 = start[(i + 1) << 3];
    float acc = 0.f;
    for (int p = s + eo; p < e2; p += 4) {
        int2 pr = pay[p];
        acc += __int_as_float(pr.y) * t[((size_t)pr.x << 4) + c];
    }
    acc += __shfl_xor(acc, 16);
    acc += __shfl_xor(acc, 32);
    float v = dinv[i] * (acc + t[((size_t)i << 4) + c]) + b[c];
    if (lane < 16) h[((size_t)i << 4) + c] = fmaxf(v, 0.f);
}

// layer-2 variant: fuse bias+relu+output projection, write out[i] directly.

__global__ __launch_bounds__(256) void k_agg_out(const int* __restrict__ start,
                                                 const int2* __restrict__ pay,
                                                 const float* __restrict__ dinv,
                                                 const float* __restrict__ t,
                                                 const float* __restrict__ b,
                                                 const float* __restrict__ Wout,
                                                 const float* __restrict__ bout,
                                                 float* __restrict__ out) {
    int i = (blockIdx.x * 256 + threadIdx.x) >> 6;
    if (i >= N_NODES) return;
    int lane = threadIdx.x & 63;
    int eo = lane >> 4;
    int c  = lane & 15;
    int s = start[i << 3], e2 = start[(i + 1) << 3];
    float acc = 0.f;
    for (int p = s + eo; p < e2; p += 4) {
        int2 pr = pay[p];
        acc += __int_as_float(pr.y) * t[((size_t)pr.x << 4) + c];
    }
    acc += __shfl_xor(acc, 16);
    acc += __shfl_xor(acc, 32);
    float v = dinv[i] * (acc + t[((size_t)i << 4) + c]) + b[c];
    float r = fmaxf(v, 0.f) * Wout[c];
#pragma unroll
    for (int m = 8; m >= 1; m >>= 1) r += __shfl_xor(r, m);
    if (lane == 0) out[i] = r + bout[0];
}

// ---------------- GEMM h@W2, epilogue x dinv ----------------

__global__ __launch_bounds__(256) void k_gemm_hid(const float* __restrict__ h,
                                                  const float* __restrict__ W,
                                                  const float* __restrict__ dinv,
                                                  float* __restrict__ t) {
    __shared__ float ws[HID * HID];
    int tid = threadIdx.x;
    if (tid < HID * HID) ws[tid] = W[tid];
    __syncthreads();
    int idx = blockIdx.x * 256 + tid;
    if (idx >= N_NODES * HID) return;
    int i = idx >> 4, c = idx & 15;
    const float* hr = h + (size_t)i * HID;
    float acc = 0.f;
#pragma unroll
    for (int k = 0; k < HID; ++k) acc += hr[k] * ws[k * HID + c];
    t[idx] = dinv[i] * acc;
}

extern "C" void kernel_launch(void* const* d_in, const int* in_sizes, int n_in,
                              void* d_out, int out_size, void* d_ws, size_t ws_size,
                              hipStream_t stream) {
    const float* x    = (const float*)d_in[0];
    const int*   eidx = (const int*)d_in[1];
    const float* ew   = (const float*)d_in[2];
    const float* W1   = (const float*)d_in[5];
    const float* b1   = (const float*)d_in[6];
    const float* W2   = (const float*)d_in[7];
    const float* b2   = (const float*)d_in[8];
    const float* Wout = (const float*)d_in[9];
    const float* bout = (const float*)d_in[10];
    float* out = (float*)d_out;

    const int* row = eidx;             // edge_index[0] (src)
    const int* col = eidx + N_EDGES;   // edge_index[1] (dst)

    // workspace layout (4B units); pay offset is 8B-aligned (901032 even)
    int*   cnt  = (int*)d_ws;                          // 800008
    int*   bsum = cnt + 800008;                        // 1024
    float* dinv = (float*)(bsum + 1024);               // N
    int2*  pay  = (int2*)(dinv + N_NODES);             // E int2 (6.4M ints)
    int*   rank = (int*)(pay + N_EDGES);               // E ints (dead after place)
    float* t    = (float*)rank;                        // N*16 (aliases rank)
    float* h    = t + (size_t)N_NODES * HID;           // N*16 (aliases rank)

    const int B = 256;
    const int gE   = (N_EDGES + B - 1) / B;            // 12500
    const int gN16 = N_NODES / 16;                     // 6250
    const int gNH  = (N_NODES * HID + B - 1) / B;      // 6250
    const int gW   = (N_NODES * 64 + B - 1) / B;       // 25000 (wave per node)
    const int gZ   = (SCAN_N + B - 1) / B;

    // CSR build
    k_zero<<<gZ, B, 0, stream>>>(cnt, SCAN_N);
    k_hist<<<gE, B, 0, stream>>>(col, cnt, rank);
    k_scan1<<<SCAN_NB, SCAN_B, 0, stream>>>(cnt, bsum);
    k_scan2<<<1, 64, 0, stream>>>(bsum);
    k_scan3<<<SCAN_NB, SCAN_B, 0, stream>>>(cnt, bsum);
    k_place<<<gE, B, 0, stream>>>(row, col, ew, cnt, rank, pay);

    // normalization
    k_deg<<<gW, B, 0, stream>>>(cnt, pay, dinv);

    // layer 1
    k_gemm_in<<<gN16, B, 0, stream>>>(x, W1, dinv, t);
    k_agg_mid<<<gW, B, 0, stream>>>(cnt, pay, dinv, t, b1, h);

    // layer 2 (+ fused output projection)
    k_gemm_hid<<<gNH, B, 0, stream>>>(h, W2, dinv, t);
    k_agg_out<<<gW, B, 0, stream>>>(cnt, pay, dinv, t, b2, Wout, bout, out);
}